// Round 4
// baseline (36.734 us; speedup 1.0000x reference)
//
#include <hip/hip_runtime.h>
#include <math.h>

// Diversity8: loss = mean_b( 0.3 * 0.5 * sum_{m!=n} corr(p_m[b], p_n[b]) )
// Streaming form: per model m, fold w_m into running (tsum, sw2) per element,
// then cross_b = sum_c [ tsum_c^2 - sw2_c ]. Live set ~64 data VGPRs.
// One wave per sample, 4 waves per block, no LDS, no barriers, no max-pass
// (logits/20 in [-0.3,0.3] -> exp is safe; softmax is shift-invariant).

constexpr int NC   = 1000;
constexpr int NC4  = 250;     // float4 chunks per row
constexpr int NM   = 8;
constexpr float TINV = 1.0f / 20.0f;
constexpr float INVC = 1.0f / (float)NC;

__device__ __forceinline__ float waveSum(float v) {
#pragma unroll
    for (int o = 32; o > 0; o >>= 1) v += __shfl_xor(v, o, 64);
    return v;
}
__device__ __forceinline__ double waveSumD(double v) {
#pragma unroll
    for (int o = 32; o > 0; o >>= 1) v += __shfl_xor(v, o, 64);
    return v;
}

__global__ __launch_bounds__(256, 4) void div8_main(
    const float* __restrict__ in0, const float* __restrict__ in1,
    const float* __restrict__ in2, const float* __restrict__ in3,
    const float* __restrict__ in4, const float* __restrict__ in5,
    const float* __restrict__ in6, const float* __restrict__ in7,
    float* __restrict__ part, int B)
{
    const int wid  = threadIdx.x >> 6;
    const int lane = threadIdx.x & 63;
    const int b    = blockIdx.x * 4 + wid;   // one wave per sample
    if (b >= B) return;
    const bool act3 = lane < (NC4 - 3 * 64); // lane < 58: chunk j=3 valid

    const float* rows[NM] = {
        in0 + (size_t)b * NC, in1 + (size_t)b * NC,
        in2 + (size_t)b * NC, in3 + (size_t)b * NC,
        in4 + (size_t)b * NC, in5 + (size_t)b * NC,
        in6 + (size_t)b * NC, in7 + (size_t)b * NC };

    // running per-element accumulators: tsum_c = sum_m w_m[c], sw2_c = sum_m w_m[c]^2
    float4 t4[4], s4[4];
#pragma unroll
    for (int j = 0; j < 4; ++j) {
        t4[j] = make_float4(0.f, 0.f, 0.f, 0.f);
        s4[j] = make_float4(0.f, 0.f, 0.f, 0.f);
    }

#pragma unroll
    for (int m = 0; m < NM; ++m) {
        const float4* p = reinterpret_cast<const float4*>(rows[m]);

        // load + exp (pads load -inf -> exp = 0, contributes nothing to S)
        float4 e[4];
#pragma unroll
        for (int j = 0; j < 4; ++j) {
            float4 v = (j < 3) ? p[lane + 64 * j]
                     : (act3 ? p[lane + 192]
                             : make_float4(-INFINITY, -INFINITY, -INFINITY, -INFINITY));
            e[j].x = __expf(v.x * TINV);
            e[j].y = __expf(v.y * TINV);
            e[j].z = __expf(v.z * TINV);
            e[j].w = __expf(v.w * TINV);
        }

        // S = sum_c e_c
        float s = 0.f;
#pragma unroll
        for (int j = 0; j < 4; ++j)
            s += (e[j].x + e[j].y) + (e[j].z + e[j].w);
        const float S  = waveSum(s);
        const float SC = S * INVC;            // mean of e over classes

        // q' = sum_c (e_c - S/C)^2   (cancellation-free; w = (e - S/C)/sqrt(q'))
        float qq = 0.f;
#pragma unroll
        for (int j = 0; j < 4; ++j) {
            if (j == 3 && !act3) continue;    // pads would wrongly add SC^2
            float u0 = e[j].x - SC;
            float u1 = e[j].y - SC;
            float u2 = e[j].z - SC;
            float u3 = e[j].w - SC;
            qq = fmaf(u0, u0, fmaf(u1, u1, fmaf(u2, u2, fmaf(u3, u3, qq))));
        }
        const float qt = waveSum(qq);
        const float rm = 1.0f / sqrtf(qt);
        const float bmv = -SC * rm;

        // fold w = e*rm + bmv into running accumulators, then e_m dies
#pragma unroll
        for (int j = 0; j < 4; ++j) {
            if (j == 3 && !act3) continue;    // keep pad accumulators at 0
            float w;
            w = fmaf(e[j].x, rm, bmv); t4[j].x += w; s4[j].x = fmaf(w, w, s4[j].x);
            w = fmaf(e[j].y, rm, bmv); t4[j].y += w; s4[j].y = fmaf(w, w, s4[j].y);
            w = fmaf(e[j].z, rm, bmv); t4[j].z += w; s4[j].z = fmaf(w, w, s4[j].z);
            w = fmaf(e[j].w, rm, bmv); t4[j].w += w; s4[j].w = fmaf(w, w, s4[j].w);
        }
    }

    // cross_b = sum_c [ tsum_c^2 - sw2_c ]  (pads: 0 - 0 = 0)
    double cr = 0.0;
#pragma unroll
    for (int j = 0; j < 4; ++j) {
        cr += (double)fmaf(t4[j].x, t4[j].x, -s4[j].x);
        cr += (double)fmaf(t4[j].y, t4[j].y, -s4[j].y);
        cr += (double)fmaf(t4[j].z, t4[j].z, -s4[j].z);
        cr += (double)fmaf(t4[j].w, t4[j].w, -s4[j].w);
    }
    cr = waveSumD(cr);
    if (lane == 0) part[b] = (float)cr;   // = sum_{m!=n} G_mn for sample b
}

__global__ __launch_bounds__(256) void div8_final(
    const float* __restrict__ part, float* __restrict__ out, int B)
{
    const int t = threadIdx.x;
    double acc = 0.0;
    for (int i = t; i < B; i += 256) acc += (double)part[i];  // fixed order: deterministic
    acc = waveSumD(acc);
    __shared__ double redd[4];
    if ((t & 63) == 0) redd[t >> 6] = acc;
    __syncthreads();
    if (t == 0) {
        double tot = (redd[0] + redd[1]) + (redd[2] + redd[3]);
        // loss = mean( 0.3 * 0.5 * cross_b )
        out[0] = (float)(tot * (0.5 * 0.3 / (double)B));
    }
}

extern "C" void kernel_launch(void* const* d_in, const int* in_sizes, int n_in,
                              void* d_out, int out_size, void* d_ws, size_t ws_size,
                              hipStream_t stream)
{
    const float* a0 = (const float*)d_in[0];
    const float* a1 = (const float*)d_in[1];
    const float* a2 = (const float*)d_in[2];
    const float* a3 = (const float*)d_in[3];
    const float* a4 = (const float*)d_in[4];
    const float* a5 = (const float*)d_in[5];
    const float* a6 = (const float*)d_in[6];
    const float* a7 = (const float*)d_in[7];
    const int B = in_sizes[0] / NC;   // 4096

    float* part = (float*)d_ws;       // B floats of scratch

    const int grid = (B + 3) / 4;     // 4 samples (waves) per block
    div8_main<<<grid, 256, 0, stream>>>(a0, a1, a2, a3, a4, a5, a6, a7, part, B);
    div8_final<<<1, 256, 0, stream>>>(part, (float*)d_out, B);
}